// Round 8
// baseline (221.504 us; speedup 1.0000x reference)
//
#include <hip/hip_runtime.h>
#include <math.h>

#define C 128
#define N 4096
#define BP 8
#define TN 64

typedef __attribute__((ext_vector_type(8))) short bf16x8;
typedef __attribute__((ext_vector_type(16))) float f32x16;
typedef __attribute__((ext_vector_type(4))) int i32x4;
typedef __attribute__((ext_vector_type(16))) int i32x16;

// ---------- ws layout ----------
// [0, 64KB)   inv-norms float[16][4096] (fallback path only)
// [64KB, ...) fragment blob: [pair][mt=128][18 frags][1KB]
//   frag 0..3  = Vm hi (QK^T A, normalized tgt, i8 hi of 15-bit fixed)
//   frag 4..7  = Vm lo (i8 lo)
//   frag 8..15 = Vcm hi (PV A, raw tgt desc, bf16 RNE)
//   frag 16..17= extras rows x/y/w/1 (bf16, rest zero)
#define PREP_OFF 65536
#define FRAGS_PER_MT 18
#define SUBT_BYTES (FRAGS_PER_MT * 1024)
#define BLOB_BYTES ((size_t)BP * 128 * FRAGS_PER_MT * 1024)

__device__ __forceinline__ unsigned short bf16rnd(float x) {
  unsigned u = __float_as_uint(x);
  u += 0x7fffu + ((u >> 16) & 1u);
  return (unsigned short)(u >> 16);
}
__device__ __forceinline__ float bf16up(unsigned short h) {
  return __uint_as_float(((unsigned)h) << 16);
}
__device__ __forceinline__ int rne2(float x, float y) {
  unsigned ux = __float_as_uint(x); ux += 0x7fffu + ((ux >> 16) & 1u);
  unsigned uy = __float_as_uint(y); uy += 0x7fffu + ((uy >> 16) & 1u);
  return (int)__builtin_amdgcn_perm(uy, ux, 0x07060302u);
}
__device__ __forceinline__ int trunc2(float x, float y) {
  return (int)__builtin_amdgcn_perm(__float_as_uint(y), __float_as_uint(x), 0x07060302u);
}
__device__ __forceinline__ float truncres(float x) {
  return x - __uint_as_float(__float_as_uint(x) & 0xffff0000u);
}
__device__ __forceinline__ int pk4(int a, int b, int c, int d) {
  return (a & 255) | ((b & 255) << 8) | ((c & 255) << 16) | ((d & 255) << 24);
}

// Kernel 1 (fallback only)
__global__ __launch_bounds__(256) void knorm_inv(const float* __restrict__ desc,
                                                 float* __restrict__ inv) {
  int n = blockIdx.x * 256 + threadIdx.x;
  int b = 2 * blockIdx.y + 1;
  const float* d = desc + (size_t)b * C * N + n;
  float ssq = 0.f;
#pragma unroll 8
  for (int c = 0; c < C; ++c) {
    float v = d[(size_t)c * N];
    ssq = fmaf(v, v, ssq);
  }
  inv[b * N + n] = 1.0f / fmaxf(sqrtf(ssq), 1e-12f);
}

// Kernel 1b: one-shot conversion of tgt tiles into fragment-order blobs.
__global__ __launch_bounds__(256) void kprep(
    const float* __restrict__ coords, const float* __restrict__ wtsp,
    const float* __restrict__ desc, unsigned char* __restrict__ blob) {
  const int mt = blockIdx.x;  // 0..127
  const int p = blockIdx.y;   // 0..7
  const int tb = 2 * p + 1;
  const int m0 = mt * 32;
  const int t = threadIdx.x;
  const int ks = t >> 6;
  const int h = (t >> 5) & 1;
  const int l31 = t & 31;

  __shared__ float rss[8][32];

  const float* tgtd = desc + (size_t)tb * C * N;
  unsigned char* bl = blob + ((size_t)(p * 128 + mt) * FRAGS_PER_MT) * 1024;

  float vr[16];
  float part = 0.f;
#pragma unroll
  for (int i = 0; i < 16; ++i) {
    float v = tgtd[(size_t)(32 * ks + 16 * h + i) * N + m0 + l31];
    vr[i] = v;
    part = fmaf(v, v, part);
  }
  rss[ks * 2 + h][l31] = part;
  __syncthreads();
  float ssq = 0.f;
#pragma unroll
  for (int u = 0; u < 8; ++u) ssq += rss[u][l31];
  const float invm = 1.0f / fmaxf(sqrtf(ssq), 1e-12f);

  {
    int hb[16], lb[16];
#pragma unroll
    for (int i = 0; i < 16; ++i) {
      int q = (int)rintf(vr[i] * invm * 16384.f);
      int hi = (q + 128) >> 8;
      hb[i] = hi;
      lb[i] = q - (hi << 8);
    }
    int4 ph = make_int4(pk4(hb[0], hb[1], hb[2], hb[3]), pk4(hb[4], hb[5], hb[6], hb[7]),
                        pk4(hb[8], hb[9], hb[10], hb[11]), pk4(hb[12], hb[13], hb[14], hb[15]));
    int4 pl = make_int4(pk4(lb[0], lb[1], lb[2], lb[3]), pk4(lb[4], lb[5], lb[6], lb[7]),
                        pk4(lb[8], lb[9], lb[10], lb[11]), pk4(lb[12], lb[13], lb[14], lb[15]));
    int lane = 32 * h + l31;
    *(int4*)(bl + (size_t)ks * 1024 + lane * 16) = ph;
    *(int4*)(bl + (size_t)(4 + ks) * 1024 + lane * 16) = pl;
  }

#pragma unroll
  for (int it = 0; it < 4; ++it) {
    int e = t + 256 * it;
    int c = e >> 3, mq = e & 7;
    float4 v = *(const float4*)&tgtd[(size_t)c * N + m0 + 4 * mq];
    int f = (c >> 5) * 2 + (mq >> 2);
    int slot = (c & 31) + 32 * ((mq >> 1) & 1);
    int2 pk;
    pk.x = rne2(v.x, v.y);
    pk.y = rne2(v.z, v.w);
    *(int2*)(bl + (size_t)(8 + f) * 1024 + slot * 16 + (mq & 1) * 8) = pk;
  }

  if (t < 128) {
    int fe = t >> 6, slot = t & 63, r = slot & 31, hh = slot >> 5;
    int4 pk = make_int4(0, 0, 0, 0);
    if (r < 4) {
      const float* rp = (r == 0)   ? coords + (size_t)tb * 2 * N
                        : (r == 1) ? coords + (size_t)tb * 2 * N + N
                                   : wtsp + (size_t)tb * N;
      int mb = m0 + 16 * fe + 8 * hh;
      float v[8];
#pragma unroll
      for (int i = 0; i < 8; ++i) v[i] = (r == 3) ? 1.0f : rp[mb + i];
      pk.x = rne2(v[0], v[1]);
      pk.y = rne2(v[2], v[3]);
      pk.z = rne2(v[4], v[5]);
      pk.w = rne2(v[6], v[7]);
    }
    *(int4*)(bl + (size_t)(16 + fe) * 1024 + slot * 16) = pk;
  }
}

// ---------- main kernel v8: barrier-free K-loop ----------
// Each wave privately DMAs its 8 QK frags into its own 16 KB LDS dbuf;
// same-wave vmcnt ordering (manual s_waitcnt vmcnt(8) safety net) replaces
// __syncthreads entirely. V/extras frags direct global->VGPR. Waves free-run
// and de-phase so MFMA/VALU/latency overlap across the 2 waves/SIMD.
#define LDS_SHORTS 32768  // 4 waves x 2 bufs x 4096 shorts (8 frags) = 64 KB

__global__ __launch_bounds__(256, 2) void kmain(
    const float* __restrict__ wtsp, const float* __restrict__ desc,
    const unsigned char* __restrict__ blob, float* __restrict__ out) {
  const int bid = blockIdx.x;
  const int p = bid & 7;        // XCD-affine pair
  const int ntile = bid >> 3;
  const int sb = 2 * p;
  const int n0 = ntile * TN;
  const int tid = threadIdx.x;
  const int w = tid >> 6;
  const int ln = tid & 63;
  const int l31 = ln & 31;
  const int h = ln >> 5;
  const int wn = w & 1;   // n-slab
  const int st = w >> 1;  // m-subtile

  __shared__ __align__(16) short L[LDS_SHORTS];

  const float* srcd = desc + (size_t)sb * C * N;
  const unsigned char* wblob = blob + (size_t)p * 128 * SUBT_BYTES;
  const int nn = n0 + 32 * wn + l31;

  // ---- Q setup: norm + resident i8 hi/lo B-fragments ----
  float ssq = 0.f;
#pragma unroll
  for (int ks = 0; ks < 4; ++ks) {
#pragma unroll
    for (int i = 0; i < 16; ++i) {
      float v = srcd[(size_t)(32 * ks + 16 * h + i) * N + nn];
      ssq = fmaf(v, v, ssq);
    }
  }
  ssq += __shfl_xor(ssq, 32);
  const float invs = 1.0f / fmaxf(sqrtf(ssq), 1e-12f);

  i32x4 Qhi[4], Qlo[4];
#pragma unroll
  for (int ks = 0; ks < 4; ++ks) {
    int hb[16], lb[16];
#pragma unroll
    for (int i = 0; i < 16; ++i) {
      float v = srcd[(size_t)(32 * ks + 16 * h + i) * N + nn] * invs;
      int q = (int)rintf(v * 16384.f);
      int hi = (q + 128) >> 8;
      hb[i] = hi;
      lb[i] = q - (hi << 8);
    }
    i32x4 qh = {pk4(hb[0], hb[1], hb[2], hb[3]), pk4(hb[4], hb[5], hb[6], hb[7]),
                pk4(hb[8], hb[9], hb[10], hb[11]), pk4(hb[12], hb[13], hb[14], hb[15])};
    i32x4 ql = {pk4(lb[0], lb[1], lb[2], lb[3]), pk4(lb[4], lb[5], lb[6], lb[7]),
                pk4(lb[8], lb[9], lb[10], lb[11]), pk4(lb[12], lb[13], lb[14], lb[15])};
    Qhi[ks] = qh;
    Qlo[ks] = ql;
  }

  f32x16 acc[5];
#pragma unroll
  for (int t = 0; t < 5; ++t)
#pragma unroll
    for (int r = 0; r < 16; ++r) acc[t][r] = 0.f;

  i32x16 zz;
#pragma unroll
  for (int r = 0; r < 16; ++r) zz[r] = 0;

  // wave-private DMA of this wave's 8 QK frags for iter 'it' into buf (it&1)
  auto issue_dma = [&](int it) {
    const unsigned char* s0 =
        wblob + (size_t)(it * 2 + st) * SUBT_BYTES + ln * 16;
    short* dst = &L[w * 8192 + (it & 1) * 4096];
#pragma unroll
    for (int f = 0; f < 8; ++f) {
      __builtin_amdgcn_global_load_lds(
          (const void __attribute__((address_space(1)))*)(s0 + (size_t)f * 1024),
          (void __attribute__((address_space(3)))*)&dst[f * 512], 16, 0, 0);
    }
  };
  // direct V loads: 5 frags of s2-group
  auto loadV = [&](int it2, int s2, bf16x8* V) {
    const unsigned char* vb =
        wblob + (size_t)(it2 * 2 + st) * SUBT_BYTES + (size_t)(8 + s2) * 1024 + ln * 16;
#pragma unroll
    for (int t = 0; t < 5; ++t) V[t] = *(const bf16x8*)(vb + (size_t)(2 * t) * 1024);
  };

  bf16x8 V0[5], V1[5];

  issue_dma(0);
  loadV(0, 0, V0);

  for (int it = 0; it < 64; ++it) {
    if (it < 63) issue_dma(it + 1);
    // vmcnt(8): leave next iter's 8 DMAs in flight, everything older (this
    // iter's DMA + previous V loads) retired -> this wave's buffer is valid.
    __builtin_amdgcn_s_waitcnt(0x0F78);

    const short* vb = &L[w * 8192 + (it & 1) * 4096];

    // ---- QK^T: exact 15-bit i8, 4 MFMAs/ks in 3 accumulator chains ----
    i32x16 Shh, Sx, Sll;
    {
      i32x4 ah = *(const i32x4*)&vb[0 * 512 + ln * 8];
      i32x4 al = *(const i32x4*)&vb[4 * 512 + ln * 8];
      Shh = __builtin_amdgcn_mfma_i32_32x32x32_i8(ah, Qhi[0], zz, 0, 0, 0);
      Sx = __builtin_amdgcn_mfma_i32_32x32x32_i8(ah, Qlo[0], zz, 0, 0, 0);
      Sll = __builtin_amdgcn_mfma_i32_32x32x32_i8(al, Qlo[0], zz, 0, 0, 0);
      Sx = __builtin_amdgcn_mfma_i32_32x32x32_i8(al, Qhi[0], Sx, 0, 0, 0);
    }
#pragma unroll
    for (int ks = 1; ks < 4; ++ks) {
      i32x4 ah = *(const i32x4*)&vb[ks * 512 + ln * 8];
      i32x4 al = *(const i32x4*)&vb[(4 + ks) * 512 + ln * 8];
      Shh = __builtin_amdgcn_mfma_i32_32x32x32_i8(ah, Qhi[ks], Shh, 0, 0, 0);
      Sx = __builtin_amdgcn_mfma_i32_32x32x32_i8(ah, Qlo[ks], Sx, 0, 0, 0);
      Sll = __builtin_amdgcn_mfma_i32_32x32x32_i8(al, Qlo[ks], Sll, 0, 0, 0);
      Sx = __builtin_amdgcn_mfma_i32_32x32x32_i8(al, Qhi[ks], Sx, 0, 0, 0);
    }

    // V group 1 for this iter (latency hidden behind exp phase)
    loadV(it, 1, V1);

    // ---- P = exp2(k2*dot' + b2); dot' = 65536*Shh + 256*Sx + Sll ----
    int pp[8], xpp[8];
#pragma unroll
    for (int q = 0; q < 4; ++q) {
      float pv[4];
#pragma unroll
      for (int j = 0; j < 4; ++j) {
        int r = 4 * q + j;
        int tot = (Shh[r] << 8) + Sx[r];  // |tot| < 2^27.1
        float sf = fmaf((float)tot, 256.f, (float)Sll[r]);
        // 100/2^28*log2(e), -60*log2(e)
        pv[j] = exp2f(fmaf(sf, 5.3744005e-07f, -86.561646f));
      }
      pp[2 * q] = rne2(pv[0], pv[1]);
      pp[2 * q + 1] = rne2(pv[2], pv[3]);
    }
#pragma unroll
    for (int j = 0; j < 8; ++j) xpp[j] = __shfl_xor(pp[j], 32);

    // ---- PV s2=0 ----
    {
      int4 bi;
      if (h == 0)
        bi = make_int4(pp[0], pp[1], xpp[0], xpp[1]);
      else
        bi = make_int4(xpp[2], xpp[3], pp[2], pp[3]);
      bf16x8 bh = __builtin_bit_cast(bf16x8, bi);
#pragma unroll
      for (int t = 0; t < 5; ++t)
        acc[t] = __builtin_amdgcn_mfma_f32_32x32x16_bf16(V0[t], bh, acc[t], 0, 0, 0);
    }

    // prefetch next iter's V group 0
    {
      int itn = (it < 63) ? it + 1 : 63;
      loadV(itn, 0, V0);
    }

    // ---- PV s2=1 ----
    {
      int4 bi;
      if (h == 0)
        bi = make_int4(pp[4], pp[5], xpp[4], xpp[5]);
      else
        bi = make_int4(xpp[6], xpp[7], pp[6], pp[7]);
      bf16x8 bh = __builtin_bit_cast(bf16x8, bi);
#pragma unroll
      for (int t = 0; t < 5; ++t)
        acc[t] = __builtin_amdgcn_mfma_f32_32x32x16_bf16(V1[t], bh, acc[t], 0, 0, 0);
    }
  }

  // ---- cross-subtile reduction + epilogue ----
  __syncthreads();
  float* red = (float*)&L[0];
  if (st == 1) {
#pragma unroll
    for (int t = 0; t < 5; ++t)
#pragma unroll
      for (int r = 0; r < 16; ++r)
        red[wn * 5120 + t * 1024 + r * 64 + ln] = acc[t][r];
  }
  __syncthreads();

  if (st == 0) {
#pragma unroll
    for (int t = 0; t < 5; ++t)
#pragma unroll
      for (int r = 0; r < 16; ++r)
        acc[t][r] += red[wn * 5120 + t * 1024 + r * 64 + ln];

    float ssqd = 0.f, dotr = 0.f;
#pragma unroll
    for (int t = 0; t < 4; ++t) {
#pragma unroll
      for (int r = 0; r < 16; ++r) {
        int c = 32 * t + (r & 3) + 8 * (r >> 2) + 4 * h;
        float d = acc[t][r];
        ssqd = fmaf(d, d, ssqd);
        dotr = fmaf(d, srcd[(size_t)c * N + nn], dotr);
      }
    }
    ssqd += __shfl_xor(ssqd, 32);
    dotr += __shfl_xor(dotr, 32);
    if (h == 0) {
      float x = acc[4][0], y = acc[4][1], wv = acc[4][2], Ld = acc[4][3];
      float invL = 1.0f / Ld;
      float nrm = fmaxf(sqrtf(ssqd), 1e-30f);
      float score = dotr / (nrm * 128.0f);
      float sw = wtsp[(size_t)sb * N + nn];
      out[(size_t)p * 2 * N + nn] = x * invL;
      out[(size_t)p * 2 * N + N + nn] = y * invL;
      out[(size_t)(BP * 2 * N) + (size_t)p * N + nn] =
          0.5f * (score + 1.0f) * sw * wv * invL;
    }
  }
}

// ================= fallback (round-3) path, used if ws too small ===========
#define OFF_VMH3 0
#define OFF_VML3 8192
#define OFF_VCM3 16384
#define OFF_PH3 26624
#define LDS3_SHORTS 30720

__global__ __launch_bounds__(256, 2) void kmain_v3(
    const float* __restrict__ coords, const float* __restrict__ wtsp,
    const float* __restrict__ desc, const float* __restrict__ inv,
    float* __restrict__ out) {
  const int ntile = blockIdx.x;
  const int p = blockIdx.y;
  const int sb = 2 * p, tb = 2 * p + 1;
  const int n0 = ntile * TN;
  const int tid = threadIdx.x;
  const int w = tid >> 6;
  const int ln = tid & 63;
  const int l31 = ln & 31;
  const int h = ln >> 5;
  const int wn = w & 1;
  const int st = w >> 1;
  const int pt = wn * 64 + ln;

  __shared__ __align__(16) short L[LDS3_SHORTS];

  const float* srcd = desc + (size_t)sb * C * N;
  const float* tgtd = desc + (size_t)tb * C * N;
  const float* invtg = inv + tb * N;
  const float* tcx = coords + (size_t)tb * 2 * N;
  const float* tcy = tcx + N;
  const float* twp = wtsp + (size_t)tb * N;
  const int nn = n0 + 32 * wn + l31;

  float ssq = 0.f;
#pragma unroll
  for (int k = 0; k < 8; ++k) {
    int cb = 16 * k + 8 * h;
#pragma unroll
    for (int i = 0; i < 8; ++i) {
      float v = srcd[(size_t)(cb + i) * N + nn];
      ssq = fmaf(v, v, ssq);
    }
  }
  ssq += __shfl_xor(ssq, 32);
  float invs = 1.0f / fmaxf(sqrtf(ssq), 1e-12f);

  bf16x8 Qh[8], Ql[8];
#pragma unroll
  for (int k = 0; k < 8; ++k) {
    int cb = 16 * k + 8 * h;
    bf16x8 qh, ql;
#pragma unroll
    for (int i = 0; i < 8; ++i) {
      float v = srcd[(size_t)(cb + i) * N + nn] * invs;
      unsigned short hs = bf16rnd(v);
      unsigned short ls = bf16rnd(v - bf16up(hs));
      qh[i] = (short)hs;
      ql[i] = (short)ls;
    }
    Qh[k] = qh;
    Ql[k] = ql;
  }

  {
    int* z = (int*)&L[OFF_VCM3];
    for (int i = tid; i < 1024; i += 256) {
      int sI = i >> 9, j = i & 511;
      z[sI * 2560 + 2048 + j] = 0;
    }
  }

  f32x16 acc[5];
#pragma unroll
  for (int t = 0; t < 5; ++t)
#pragma unroll
    for (int r = 0; r < 16; ++r) acc[t][r] = 0.f;

  const int er = pt & 3, ehh = (pt >> 2) & 1, esf = pt >> 3;
  const float* erp = (er == 0) ? tcx : (er == 1) ? tcy : twp;

  float vm[32];
  float invm = 0.f;
  float4 exv0 = make_float4(1, 1, 1, 1), exv1 = exv0;

  auto prefetch = [&](int ms0) {
#pragma unroll
    for (int k = 0; k < 4; ++k) {
      int cb = 16 * (2 * k + wn) + 8 * h;
#pragma unroll
      for (int i = 0; i < 8; ++i)
        vm[k * 8 + i] = tgtd[(size_t)(cb + i) * N + ms0 + l31];
    }
    invm = invtg[ms0 + l31];
    if (pt < 16 && er < 3) {
      int mb = ms0 + 16 * esf + 8 * ehh;
      exv0 = *(const float4*)&erp[mb];
      exv1 = *(const float4*)&erp[mb + 4];
    }
  };

  prefetch(32 * st);

  for (int m0 = 0; m0 < N; m0 += 64) {
    const int ms0 = m0 + 32 * st;
    float4 vc[8];
#pragma unroll
    for (int it = 0; it < 8; ++it) {
      int e = pt + 128 * it, c = e >> 3, mq = e & 7;
      vc[it] = *(const float4*)&tgtd[(size_t)c * N + ms0 + 4 * mq];
    }
#pragma unroll
    for (int k = 0; k < 4; ++k) {
      int kk = 2 * k + wn;
      int hw[4], lw[4];
#pragma unroll
      for (int j = 0; j < 4; ++j) {
        float v0 = vm[k * 8 + 2 * j] * invm;
        float v1 = vm[k * 8 + 2 * j + 1] * invm;
        hw[j] = trunc2(v0, v1);
        lw[j] = trunc2(truncres(v0), truncres(v1));
      }
      *(int4*)&L[OFF_VMH3 + st * 4096 + kk * 512 + ln * 8] =
          make_int4(hw[0], hw[1], hw[2], hw[3]);
      *(int4*)&L[OFF_VML3 + st * 4096 + kk * 512 + ln * 8] =
          make_int4(lw[0], lw[1], lw[2], lw[3]);
    }
#pragma unroll
    for (int it = 0; it < 8; ++it) {
      int e = pt + 128 * it, c = e >> 3, mq = e & 7;
      float4 v = vc[it];
      int f = (c >> 5) * 2 + (mq >> 2);
      int slot = (c & 31) + 32 * ((mq >> 1) & 1);
      int2 pk;
      pk.x = rne2(v.x, v.y);
      pk.y = rne2(v.z, v.w);
      *(int2*)&L[OFF_VCM3 + st * 5120 + f * 512 + slot * 8 + (mq & 1) * 4] = pk;
    }
    if (pt < 16) {
      int4 pk;
      pk.x = rne2(exv0.x, exv0.y);
      pk.y = rne2(exv0.z, exv0.w);
      pk.z = rne2(exv1.x, exv1.y);
      pk.w = rne2(exv1.z, exv1.w);
      *(int4*)&L[OFF_VCM3 + st * 5120 + (8 + esf) * 512 + (er + 32 * ehh) * 8] = pk;
    }
    __syncthreads();
    if (m0 + 64 < N) prefetch(ms0 + 64);

    f32x16 S;
#pragma unroll
    for (int r = 0; r < 16; ++r) S[r] = 0.f;
    const short* vmh = &L[OFF_VMH3 + st * 4096];
    const short* vml = &L[OFF_VML3 + st * 4096];
#pragma unroll
    for (int k = 0; k < 8; ++k) {
      bf16x8 ah = *(const bf16x8*)&vmh[k * 512 + ln * 8];
      bf16x8 al = *(const bf16x8*)&vml[k * 512 + ln * 8];
      S = __builtin_amdgcn_mfma_f32_32x32x16_bf16(al, Qh[k], S, 0, 0, 0);
      S = __builtin_amdgcn_mfma_f32_32x32x16_bf16(ah, Ql[k], S, 0, 0, 0);
      S = __builtin_amdgcn_mfma_f32_32x32x16_bf16(ah, Qh[k], S, 0, 0, 0);
    }
#pragma unroll
    for (int q = 0; q < 4; ++q) {
      float p0 = __expf(fmaf(S[4 * q + 0], 100.0f, -60.0f));
      float p1 = __expf(fmaf(S[4 * q + 1], 100.0f, -60.0f));
      float p2 = __expf(fmaf(S[4 * q + 2], 100.0f, -60.0f));
      float p3 = __expf(fmaf(S[4 * q + 3], 100.0f, -60.0f));
      int2 a;
      a.x = rne2(p0, p1);
      a.y = rne2(p2, p3);
      *(int2*)&L[OFF_PH3 + w * 1024 + (q >> 1) * 512 + (l31 + 32 * (q & 1)) * 8 + h * 4] = a;
    }
#pragma unroll
    for (int s2 = 0; s2 < 2; ++s2) {
      bf16x8 bh = *(const bf16x8*)&L[OFF_PH3 + w * 1024 + s2 * 512 + ln * 8];
#pragma unroll
      for (int t = 0; t < 5; ++t) {
        bf16x8 va = *(const bf16x8*)&L[OFF_VCM3 + st * 5120 + (2 * t + s2) * 512 + ln * 8];
        acc[t] = __builtin_amdgcn_mfma_f32_32x32x16_bf16(va, bh, acc[t], 0, 0, 0);
      }
    }
    __syncthreads();
  }

  float* red = (float*)&L[0];
  if (st == 1) {
#pragma unroll
    for (int t = 0; t < 5; ++t)
#pragma unroll
      for (int r = 0; r < 16; ++r)
        red[wn * 5120 + t * 1024 + r * 64 + ln] = acc[t][r];
  }
  __syncthreads();
  if (st == 0) {
#pragma unroll
    for (int t = 0; t < 5; ++t)
#pragma unroll
      for (int r = 0; r < 16; ++r)
        acc[t][r] += red[wn * 5120 + t * 1024 + r * 64 + ln];
    float ssqd = 0.f, dotr = 0.f;
#pragma unroll
    for (int t = 0; t < 4; ++t) {
#pragma unroll
      for (int r = 0; r < 16; ++r) {
        int c = 32 * t + (r & 3) + 8 * (r >> 2) + 4 * h;
        float d = acc[t][r];
        ssqd = fmaf(d, d, ssqd);
        dotr = fmaf(d, srcd[(size_t)c * N + nn], dotr);
      }
    }
    ssqd += __shfl_xor(ssqd, 32);
    dotr += __shfl_xor(dotr, 32);
    if (h == 0) {
      float x = acc[4][0], y = acc[4][1], wv = acc[4][2], Ld = acc[4][3];
      float invL = 1.0f / Ld;
      float nrm = fmaxf(sqrtf(ssqd), 1e-30f);
      float score = dotr / (nrm * 128.0f);
      float sw = wtsp[(size_t)sb * N + nn];
      out[(size_t)p * 2 * N + nn] = x * invL;
      out[(size_t)p * 2 * N + N + nn] = y * invL;
      out[(size_t)(BP * 2 * N) + (size_t)p * N + nn] =
          0.5f * (score + 1.0f) * sw * wv * invL;
    }
  }
}

extern "C" void kernel_launch(void* const* d_in, const int* in_sizes, int n_in,
                              void* d_out, int out_size, void* d_ws, size_t ws_size,
                              hipStream_t stream) {
  const float* coords = (const float*)d_in[0];  // [16][2][4096]
  const float* wts = (const float*)d_in[1];     // [16][1][4096]
  const float* desc = (const float*)d_in[2];    // [16][128][4096]
  float* out = (float*)d_out;                   // [8][2][4096] ++ [8][1][4096]
  float* inv = (float*)d_ws;                    // fallback inv-norms
  unsigned char* blob = (unsigned char*)d_ws + PREP_OFF;

  if (ws_size >= PREP_OFF + BLOB_BYTES) {
    kprep<<<dim3(128, BP), 256, 0, stream>>>(coords, wts, desc, blob);
    kmain<<<dim3((N / TN) * BP), 256, 0, stream>>>(wts, desc, blob, out);
  } else {
    knorm_inv<<<dim3(N / 256, BP), 256, 0, stream>>>(desc, inv);
    kmain_v3<<<dim3(N / TN, BP), 256, 0, stream>>>(coords, wts, desc, inv, out);
  }
}

// Round 9
// 203.038 us; speedup vs baseline: 1.0909x; 1.0909x over previous
//
#include <hip/hip_runtime.h>
#include <math.h>

#define C 128
#define N 4096
#define BP 8
#define TN 64

typedef __attribute__((ext_vector_type(8))) short bf16x8;
typedef __attribute__((ext_vector_type(16))) float f32x16;
typedef __attribute__((ext_vector_type(4))) int i32x4;
typedef __attribute__((ext_vector_type(16))) int i32x16;

// ---------- ws layout ----------
// [0, 64KB)   inv-norms float[16][4096] (fallback path only)
// [64KB, ...) fragment blob: [pair][mt=128][18 frags][1KB]
//   frag 0..3  = Vm hi (QK^T A, normalized tgt, i8 hi of 15-bit fixed)
//   frag 4..7  = Vm lo (i8 lo)
//   frag 8..15 = Vcm hi (PV A, raw tgt desc, bf16 RNE)
//   frag 16..17= extras rows x/y/w/1 (bf16, rest zero)
#define PREP_OFF 65536
#define FRAGS_PER_MT 18
#define SUBT_BYTES (FRAGS_PER_MT * 1024)
#define BLOB_BYTES ((size_t)BP * 128 * FRAGS_PER_MT * 1024)

__device__ __forceinline__ unsigned short bf16rnd(float x) {
  unsigned u = __float_as_uint(x);
  u += 0x7fffu + ((u >> 16) & 1u);
  return (unsigned short)(u >> 16);
}
__device__ __forceinline__ float bf16up(unsigned short h) {
  return __uint_as_float(((unsigned)h) << 16);
}
__device__ __forceinline__ int rne2(float x, float y) {
  unsigned ux = __float_as_uint(x); ux += 0x7fffu + ((ux >> 16) & 1u);
  unsigned uy = __float_as_uint(y); uy += 0x7fffu + ((uy >> 16) & 1u);
  return (int)__builtin_amdgcn_perm(uy, ux, 0x07060302u);
}
__device__ __forceinline__ int trunc2(float x, float y) {
  return (int)__builtin_amdgcn_perm(__float_as_uint(y), __float_as_uint(x), 0x07060302u);
}
__device__ __forceinline__ float truncres(float x) {
  return x - __uint_as_float(__float_as_uint(x) & 0xffff0000u);
}
__device__ __forceinline__ int pk4(int a, int b, int c, int d) {
  return (a & 255) | ((b & 255) << 8) | ((c & 255) << 16) | ((d & 255) << 24);
}

// Kernel 1 (fallback only)
__global__ __launch_bounds__(256) void knorm_inv(const float* __restrict__ desc,
                                                 float* __restrict__ inv) {
  int n = blockIdx.x * 256 + threadIdx.x;
  int b = 2 * blockIdx.y + 1;
  const float* d = desc + (size_t)b * C * N + n;
  float ssq = 0.f;
#pragma unroll 8
  for (int c = 0; c < C; ++c) {
    float v = d[(size_t)c * N];
    ssq = fmaf(v, v, ssq);
  }
  inv[b * N + n] = 1.0f / fmaxf(sqrtf(ssq), 1e-12f);
}

// Kernel 1b: one-shot conversion of tgt tiles into fragment-order blobs.
__global__ __launch_bounds__(256) void kprep(
    const float* __restrict__ coords, const float* __restrict__ wtsp,
    const float* __restrict__ desc, unsigned char* __restrict__ blob) {
  const int mt = blockIdx.x;  // 0..127
  const int p = blockIdx.y;   // 0..7
  const int tb = 2 * p + 1;
  const int m0 = mt * 32;
  const int t = threadIdx.x;
  const int ks = t >> 6;
  const int h = (t >> 5) & 1;
  const int l31 = t & 31;

  __shared__ float rss[8][32];

  const float* tgtd = desc + (size_t)tb * C * N;
  unsigned char* bl = blob + ((size_t)(p * 128 + mt) * FRAGS_PER_MT) * 1024;

  float vr[16];
  float part = 0.f;
#pragma unroll
  for (int i = 0; i < 16; ++i) {
    float v = tgtd[(size_t)(32 * ks + 16 * h + i) * N + m0 + l31];
    vr[i] = v;
    part = fmaf(v, v, part);
  }
  rss[ks * 2 + h][l31] = part;
  __syncthreads();
  float ssq = 0.f;
#pragma unroll
  for (int u = 0; u < 8; ++u) ssq += rss[u][l31];
  const float invm = 1.0f / fmaxf(sqrtf(ssq), 1e-12f);

  {
    int hb[16], lb[16];
#pragma unroll
    for (int i = 0; i < 16; ++i) {
      int q = (int)rintf(vr[i] * invm * 16384.f);
      int hi = (q + 128) >> 8;
      hb[i] = hi;
      lb[i] = q - (hi << 8);
    }
    int4 ph = make_int4(pk4(hb[0], hb[1], hb[2], hb[3]), pk4(hb[4], hb[5], hb[6], hb[7]),
                        pk4(hb[8], hb[9], hb[10], hb[11]), pk4(hb[12], hb[13], hb[14], hb[15]));
    int4 pl = make_int4(pk4(lb[0], lb[1], lb[2], lb[3]), pk4(lb[4], lb[5], lb[6], lb[7]),
                        pk4(lb[8], lb[9], lb[10], lb[11]), pk4(lb[12], lb[13], lb[14], lb[15]));
    int lane = 32 * h + l31;
    *(int4*)(bl + (size_t)ks * 1024 + lane * 16) = ph;
    *(int4*)(bl + (size_t)(4 + ks) * 1024 + lane * 16) = pl;
  }

#pragma unroll
  for (int it = 0; it < 4; ++it) {
    int e = t + 256 * it;
    int c = e >> 3, mq = e & 7;
    float4 v = *(const float4*)&tgtd[(size_t)c * N + m0 + 4 * mq];
    int f = (c >> 5) * 2 + (mq >> 2);
    int slot = (c & 31) + 32 * ((mq >> 1) & 1);
    int2 pk;
    pk.x = rne2(v.x, v.y);
    pk.y = rne2(v.z, v.w);
    *(int2*)(bl + (size_t)(8 + f) * 1024 + slot * 16 + (mq & 1) * 8) = pk;
  }

  if (t < 128) {
    int fe = t >> 6, slot = t & 63, r = slot & 31, hh = slot >> 5;
    int4 pk = make_int4(0, 0, 0, 0);
    if (r < 4) {
      const float* rp = (r == 0)   ? coords + (size_t)tb * 2 * N
                        : (r == 1) ? coords + (size_t)tb * 2 * N + N
                                   : wtsp + (size_t)tb * N;
      int mb = m0 + 16 * fe + 8 * hh;
      float v[8];
#pragma unroll
      for (int i = 0; i < 8; ++i) v[i] = (r == 3) ? 1.0f : rp[mb + i];
      pk.x = rne2(v[0], v[1]);
      pk.y = rne2(v[2], v[3]);
      pk.z = rne2(v[4], v[5]);
      pk.w = rne2(v[6], v[7]);
    }
    *(int4*)(bl + (size_t)(16 + fe) * 1024 + slot * 16) = pk;
  }
}

// ---------- main kernel v9: cross-iteration software pipeline ----------
// R7's barriered 4-buffer DMA staging + exact 15-bit i8 QK, but PV(it) is
// deferred and manually interleaved into QK(it+1)'s MFMA block so the matrix
// pipe sees a continuous stream. P crosses iterations as 8 assembled B-frag
// regs; pending V-set crosses the window barrier (its loads are drained by
// the barrier's vmcnt(0) anyway - free latency hiding).
#define LDS_SHORTS 32768  // 4 bufs x 8192 shorts = 64 KB

__global__ __launch_bounds__(256, 2) void kmain(
    const float* __restrict__ wtsp, const float* __restrict__ desc,
    const unsigned char* __restrict__ blob, float* __restrict__ out) {
  const int bid = blockIdx.x;
  const int p = bid & 7;        // XCD-affine pair
  const int ntile = bid >> 3;
  const int sb = 2 * p;
  const int n0 = ntile * TN;
  const int tid = threadIdx.x;
  const int w = tid >> 6;
  const int ln = tid & 63;
  const int l31 = ln & 31;
  const int h = ln >> 5;
  const int wn = w & 1;   // n-slab
  const int st = w >> 1;  // m-subtile

  __shared__ __align__(16) short L[LDS_SHORTS];

  const float* srcd = desc + (size_t)sb * C * N;
  const unsigned char* wblob = blob + (size_t)p * 128 * SUBT_BYTES;
  const int nn = n0 + 32 * wn + l31;

  // ---- Q setup: norm + resident i8 hi/lo B-fragments ----
  float ssq = 0.f;
#pragma unroll
  for (int ks = 0; ks < 4; ++ks) {
#pragma unroll
    for (int i = 0; i < 16; ++i) {
      float v = srcd[(size_t)(32 * ks + 16 * h + i) * N + nn];
      ssq = fmaf(v, v, ssq);
    }
  }
  ssq += __shfl_xor(ssq, 32);
  const float invs = 1.0f / fmaxf(sqrtf(ssq), 1e-12f);

  i32x4 Qhi[4], Qlo[4];
#pragma unroll
  for (int ks = 0; ks < 4; ++ks) {
    int hb[16], lb[16];
#pragma unroll
    for (int i = 0; i < 16; ++i) {
      float v = srcd[(size_t)(32 * ks + 16 * h + i) * N + nn] * invs;
      int q = (int)rintf(v * 16384.f);
      int hi = (q + 128) >> 8;
      hb[i] = hi;
      lb[i] = q - (hi << 8);
    }
    i32x4 qh = {pk4(hb[0], hb[1], hb[2], hb[3]), pk4(hb[4], hb[5], hb[6], hb[7]),
                pk4(hb[8], hb[9], hb[10], hb[11]), pk4(hb[12], hb[13], hb[14], hb[15])};
    i32x4 ql = {pk4(lb[0], lb[1], lb[2], lb[3]), pk4(lb[4], lb[5], lb[6], lb[7]),
                pk4(lb[8], lb[9], lb[10], lb[11]), pk4(lb[12], lb[13], lb[14], lb[15])};
    Qhi[ks] = qh;
    Qlo[ks] = ql;
  }

  f32x16 acc[5];
#pragma unroll
  for (int t = 0; t < 5; ++t)
#pragma unroll
    for (int r = 0; r < 16; ++r) acc[t][r] = 0.f;

  i32x16 zz;
#pragma unroll
  for (int r = 0; r < 16; ++r) zz[r] = 0;

  // DMA one iter's 16 QK frags into buffer (it & 3); wave covers 4 frags
  auto issue_dma = [&](int it) {
    const unsigned char* s0 = wblob + (size_t)(it * 2) * SUBT_BYTES + ln * 16;
    short* dst = &L[(it & 3) * 8192];
#pragma unroll
    for (int jj = 0; jj < 4; ++jj) {
      int jg = 4 * w + jj;
      const unsigned char* src = s0 + (size_t)(jg >> 3) * SUBT_BYTES + (size_t)(jg & 7) * 1024;
      __builtin_amdgcn_global_load_lds(
          (const void __attribute__((address_space(1)))*)src,
          (void __attribute__((address_space(3)))*)&dst[jg * 512], 16, 0, 0);
    }
  };
  // direct V loads: all 10 frags (V[s2*5+t] = frag 8+2t+s2)
  auto loadV = [&](int it2, bf16x8* V) {
    const unsigned char* vb =
        wblob + (size_t)(it2 * 2 + st) * SUBT_BYTES + (size_t)8 * 1024 + ln * 16;
#pragma unroll
    for (int s2 = 0; s2 < 2; ++s2)
#pragma unroll
      for (int t = 0; t < 5; ++t)
        V[s2 * 5 + t] = *(const bf16x8*)(vb + (size_t)(2 * t + s2) * 1024);
  };

  // pipeline state: pending PV = {PF0, PF1 (B-frags), Vp}
  int4 PF0 = make_int4(0, 0, 0, 0), PF1 = make_int4(0, 0, 0, 0);
  bf16x8 Vp[10];
#pragma unroll
  for (int k = 0; k < 10; ++k) Vp[k] = __builtin_bit_cast(bf16x8, make_int4(0, 0, 0, 0));

  i32x16 Shh, Sx, Sll;

  // QK(it) interleaved with pending PV; leaves S chains filled
  auto qk_pv = [&](int it) {
    const short* vb = &L[(it & 3) * 8192 + st * 4096];
    bf16x8 bh0 = __builtin_bit_cast(bf16x8, PF0);
    bf16x8 bh1 = __builtin_bit_cast(bf16x8, PF1);
    {
      i32x4 ah = *(const i32x4*)&vb[0 * 512 + ln * 8];
      i32x4 al = *(const i32x4*)&vb[4 * 512 + ln * 8];
      Shh = __builtin_amdgcn_mfma_i32_32x32x32_i8(ah, Qhi[0], zz, 0, 0, 0);
      Sx = __builtin_amdgcn_mfma_i32_32x32x32_i8(ah, Qlo[0], zz, 0, 0, 0);
      Sll = __builtin_amdgcn_mfma_i32_32x32x32_i8(al, Qlo[0], zz, 0, 0, 0);
      Sx = __builtin_amdgcn_mfma_i32_32x32x32_i8(al, Qhi[0], Sx, 0, 0, 0);
      acc[0] = __builtin_amdgcn_mfma_f32_32x32x16_bf16(Vp[0], bh0, acc[0], 0, 0, 0);
      acc[1] = __builtin_amdgcn_mfma_f32_32x32x16_bf16(Vp[1], bh0, acc[1], 0, 0, 0);
      acc[2] = __builtin_amdgcn_mfma_f32_32x32x16_bf16(Vp[2], bh0, acc[2], 0, 0, 0);
    }
    {
      i32x4 ah = *(const i32x4*)&vb[1 * 512 + ln * 8];
      i32x4 al = *(const i32x4*)&vb[5 * 512 + ln * 8];
      Shh = __builtin_amdgcn_mfma_i32_32x32x32_i8(ah, Qhi[1], Shh, 0, 0, 0);
      Sx = __builtin_amdgcn_mfma_i32_32x32x32_i8(ah, Qlo[1], Sx, 0, 0, 0);
      Sll = __builtin_amdgcn_mfma_i32_32x32x32_i8(al, Qlo[1], Sll, 0, 0, 0);
      Sx = __builtin_amdgcn_mfma_i32_32x32x32_i8(al, Qhi[1], Sx, 0, 0, 0);
      acc[3] = __builtin_amdgcn_mfma_f32_32x32x16_bf16(Vp[3], bh0, acc[3], 0, 0, 0);
      acc[4] = __builtin_amdgcn_mfma_f32_32x32x16_bf16(Vp[4], bh0, acc[4], 0, 0, 0);
    }
    {
      i32x4 ah = *(const i32x4*)&vb[2 * 512 + ln * 8];
      i32x4 al = *(const i32x4*)&vb[6 * 512 + ln * 8];
      Shh = __builtin_amdgcn_mfma_i32_32x32x32_i8(ah, Qhi[2], Shh, 0, 0, 0);
      Sx = __builtin_amdgcn_mfma_i32_32x32x32_i8(ah, Qlo[2], Sx, 0, 0, 0);
      Sll = __builtin_amdgcn_mfma_i32_32x32x32_i8(al, Qlo[2], Sll, 0, 0, 0);
      Sx = __builtin_amdgcn_mfma_i32_32x32x32_i8(al, Qhi[2], Sx, 0, 0, 0);
      acc[0] = __builtin_amdgcn_mfma_f32_32x32x16_bf16(Vp[5], bh1, acc[0], 0, 0, 0);
      acc[1] = __builtin_amdgcn_mfma_f32_32x32x16_bf16(Vp[6], bh1, acc[1], 0, 0, 0);
      acc[2] = __builtin_amdgcn_mfma_f32_32x32x16_bf16(Vp[7], bh1, acc[2], 0, 0, 0);
    }
    {
      i32x4 ah = *(const i32x4*)&vb[3 * 512 + ln * 8];
      i32x4 al = *(const i32x4*)&vb[7 * 512 + ln * 8];
      Shh = __builtin_amdgcn_mfma_i32_32x32x32_i8(ah, Qhi[3], Shh, 0, 0, 0);
      Sx = __builtin_amdgcn_mfma_i32_32x32x32_i8(ah, Qlo[3], Sx, 0, 0, 0);
      Sll = __builtin_amdgcn_mfma_i32_32x32x32_i8(al, Qlo[3], Sll, 0, 0, 0);
      Sx = __builtin_amdgcn_mfma_i32_32x32x32_i8(al, Qhi[3], Sx, 0, 0, 0);
      acc[3] = __builtin_amdgcn_mfma_f32_32x32x16_bf16(Vp[8], bh1, acc[3], 0, 0, 0);
      acc[4] = __builtin_amdgcn_mfma_f32_32x32x16_bf16(Vp[9], bh1, acc[4], 0, 0, 0);
    }
  };

  // exp + pack S -> PF0/PF1 (assembled PV B-frags)
  auto exp_pack = [&]() {
    int pp[8], xpp[8];
#pragma unroll
    for (int q = 0; q < 4; ++q) {
      float pv[4];
#pragma unroll
      for (int j = 0; j < 4; ++j) {
        int r = 4 * q + j;
        int tot = (Shh[r] << 8) + Sx[r];  // |tot| < 2^27.1
        float sf = fmaf((float)tot, 256.f, (float)Sll[r]);
        pv[j] = exp2f(fmaf(sf, 5.3744005e-07f, -86.561646f));  // 100/2^28, -60 (log2e)
      }
      pp[2 * q] = rne2(pv[0], pv[1]);
      pp[2 * q + 1] = rne2(pv[2], pv[3]);
    }
#pragma unroll
    for (int j = 0; j < 8; ++j) xpp[j] = __shfl_xor(pp[j], 32);
    if (h == 0) {
      PF0 = make_int4(pp[0], pp[1], xpp[0], xpp[1]);
      PF1 = make_int4(pp[4], pp[5], xpp[4], xpp[5]);
    } else {
      PF0 = make_int4(xpp[2], xpp[3], pp[2], pp[3]);
      PF1 = make_int4(xpp[6], xpp[7], pp[6], pp[7]);
    }
  };

  issue_dma(0);
  issue_dma(1);
  __syncthreads();  // window 0 bufs ready

  for (int j = 0; j < 32; ++j) {
    if (j < 31) {
      issue_dma(2 * j + 2);
      issue_dma(2 * j + 3);
    }
    // QK(2j) interleaved with PV(2j-1) (zeros on first window)
    qk_pv(2 * j);
    exp_pack();       // -> PF for iter 2j
    loadV(2 * j, Vp); // V for PV(2j), covered by next QK block
    // QK(2j+1) interleaved with PV(2j)
    qk_pv(2 * j + 1);
    exp_pack();           // -> PF for iter 2j+1
    loadV(2 * j + 1, Vp); // loads drained by the barrier's vmcnt(0)
    __syncthreads();      // drains next-window DMA + V loads
  }

  // final pending PV(63)
  {
    bf16x8 bh0 = __builtin_bit_cast(bf16x8, PF0);
    bf16x8 bh1 = __builtin_bit_cast(bf16x8, PF1);
#pragma unroll
    for (int t = 0; t < 5; ++t)
      acc[t] = __builtin_amdgcn_mfma_f32_32x32x16_bf16(Vp[t], bh0, acc[t], 0, 0, 0);
#pragma unroll
    for (int t = 0; t < 5; ++t)
      acc[t] = __builtin_amdgcn_mfma_f32_32x32x16_bf16(Vp[5 + t], bh1, acc[t], 0, 0, 0);
  }

  // ---- cross-subtile reduction + epilogue ----
  float* red = (float*)&L[0];
  if (st == 1) {
#pragma unroll
    for (int t = 0; t < 5; ++t)
#pragma unroll
      for (int r = 0; r < 16; ++r)
        red[wn * 5120 + t * 1024 + r * 64 + ln] = acc[t][r];
  }
  __syncthreads();

  if (st == 0) {
#pragma unroll
    for (int t = 0; t < 5; ++t)
#pragma unroll
      for (int r = 0; r < 16; ++r)
        acc[t][r] += red[wn * 5120 + t * 1024 + r * 64 + ln];

    float ssqd = 0.f, dotr = 0.f;
#pragma unroll
    for (int t = 0; t < 4; ++t) {
#pragma unroll
      for (int r = 0; r < 16; ++r) {
        int c = 32 * t + (r & 3) + 8 * (r >> 2) + 4 * h;
        float d = acc[t][r];
        ssqd = fmaf(d, d, ssqd);
        dotr = fmaf(d, srcd[(size_t)c * N + nn], dotr);
      }
    }
    ssqd += __shfl_xor(ssqd, 32);
    dotr += __shfl_xor(dotr, 32);
    if (h == 0) {
      float x = acc[4][0], y = acc[4][1], wv = acc[4][2], Ld = acc[4][3];
      float invL = 1.0f / Ld;
      float nrm = fmaxf(sqrtf(ssqd), 1e-30f);
      float score = dotr / (nrm * 128.0f);
      float sw = wtsp[(size_t)sb * N + nn];
      out[(size_t)p * 2 * N + nn] = x * invL;
      out[(size_t)p * 2 * N + N + nn] = y * invL;
      out[(size_t)(BP * 2 * N) + (size_t)p * N + nn] =
          0.5f * (score + 1.0f) * sw * wv * invL;
    }
  }
}

// ================= fallback (round-3) path, used if ws too small ===========
#define OFF_VMH3 0
#define OFF_VML3 8192
#define OFF_VCM3 16384
#define OFF_PH3 26624
#define LDS3_SHORTS 30720

__global__ __launch_bounds__(256, 2) void kmain_v3(
    const float* __restrict__ coords, const float* __restrict__ wtsp,
    const float* __restrict__ desc, const float* __restrict__ inv,
    float* __restrict__ out) {
  const int ntile = blockIdx.x;
  const int p = blockIdx.y;
  const int sb = 2 * p, tb = 2 * p + 1;
  const int n0 = ntile * TN;
  const int tid = threadIdx.x;
  const int w = tid >> 6;
  const int ln = tid & 63;
  const int l31 = ln & 31;
  const int h = ln >> 5;
  const int wn = w & 1;
  const int st = w >> 1;
  const int pt = wn * 64 + ln;

  __shared__ __align__(16) short L[LDS3_SHORTS];

  const float* srcd = desc + (size_t)sb * C * N;
  const float* tgtd = desc + (size_t)tb * C * N;
  const float* invtg = inv + tb * N;
  const float* tcx = coords + (size_t)tb * 2 * N;
  const float* tcy = tcx + N;
  const float* twp = wtsp + (size_t)tb * N;
  const int nn = n0 + 32 * wn + l31;

  float ssq = 0.f;
#pragma unroll
  for (int k = 0; k < 8; ++k) {
    int cb = 16 * k + 8 * h;
#pragma unroll
    for (int i = 0; i < 8; ++i) {
      float v = srcd[(size_t)(cb + i) * N + nn];
      ssq = fmaf(v, v, ssq);
    }
  }
  ssq += __shfl_xor(ssq, 32);
  float invs = 1.0f / fmaxf(sqrtf(ssq), 1e-12f);

  bf16x8 Qh[8], Ql[8];
#pragma unroll
  for (int k = 0; k < 8; ++k) {
    int cb = 16 * k + 8 * h;
    bf16x8 qh, ql;
#pragma unroll
    for (int i = 0; i < 8; ++i) {
      float v = srcd[(size_t)(cb + i) * N + nn] * invs;
      unsigned short hs = bf16rnd(v);
      unsigned short ls = bf16rnd(v - bf16up(hs));
      qh[i] = (short)hs;
      ql[i] = (short)ls;
    }
    Qh[k] = qh;
    Ql[k] = ql;
  }

  {
    int* z = (int*)&L[OFF_VCM3];
    for (int i = tid; i < 1024; i += 256) {
      int sI = i >> 9, j = i & 511;
      z[sI * 2560 + 2048 + j] = 0;
    }
  }

  f32x16 acc[5];
#pragma unroll
  for (int t = 0; t < 5; ++t)
#pragma unroll
    for (int r = 0; r < 16; ++r) acc[t][r] = 0.f;

  const int er = pt & 3, ehh = (pt >> 2) & 1, esf = pt >> 3;
  const float* erp = (er == 0) ? tcx : (er == 1) ? tcy : twp;

  float vm[32];
  float invm = 0.f;
  float4 exv0 = make_float4(1, 1, 1, 1), exv1 = exv0;

  auto prefetch = [&](int ms0) {
#pragma unroll
    for (int k = 0; k < 4; ++k) {
      int cb = 16 * (2 * k + wn) + 8 * h;
#pragma unroll
      for (int i = 0; i < 8; ++i)
        vm[k * 8 + i] = tgtd[(size_t)(cb + i) * N + ms0 + l31];
    }
    invm = invtg[ms0 + l31];
    if (pt < 16 && er < 3) {
      int mb = ms0 + 16 * esf + 8 * ehh;
      exv0 = *(const float4*)&erp[mb];
      exv1 = *(const float4*)&erp[mb + 4];
    }
  };

  prefetch(32 * st);

  for (int m0 = 0; m0 < N; m0 += 64) {
    const int ms0 = m0 + 32 * st;
    float4 vc[8];
#pragma unroll
    for (int it = 0; it < 8; ++it) {
      int e = pt + 128 * it, c = e >> 3, mq = e & 7;
      vc[it] = *(const float4*)&tgtd[(size_t)c * N + ms0 + 4 * mq];
    }
#pragma unroll
    for (int k = 0; k < 4; ++k) {
      int kk = 2 * k + wn;
      int hw[4], lw[4];
#pragma unroll
      for (int j = 0; j < 4; ++j) {
        float v0 = vm[k * 8 + 2 * j] * invm;
        float v1 = vm[k * 8 + 2 * j + 1] * invm;
        hw[j] = trunc2(v0, v1);
        lw[j] = trunc2(truncres(v0), truncres(v1));
      }
      *(int4*)&L[OFF_VMH3 + st * 4096 + kk * 512 + ln * 8] =
          make_int4(hw[0], hw[1], hw[2], hw[3]);
      *(int4*)&L[OFF_VML3 + st * 4096 + kk * 512 + ln * 8] =
          make_int4(lw[0], lw[1], lw[2], lw[3]);
    }
#pragma unroll
    for (int it = 0; it < 8; ++it) {
      int e = pt + 128 * it, c = e >> 3, mq = e & 7;
      float4 v = vc[it];
      int f = (c >> 5) * 2 + (mq >> 2);
      int slot = (c & 31) + 32 * ((mq >> 1) & 1);
      int2 pk;
      pk.x = rne2(v.x, v.y);
      pk.y = rne2(v.z, v.w);
      *(int2*)&L[OFF_VCM3 + st * 5120 + f * 512 + slot * 8 + (mq & 1) * 4] = pk;
    }
    if (pt < 16) {
      int4 pk;
      pk.x = rne2(exv0.x, exv0.y);
      pk.y = rne2(exv0.z, exv0.w);
      pk.z = rne2(exv1.x, exv1.y);
      pk.w = rne2(exv1.z, exv1.w);
      *(int4*)&L[OFF_VCM3 + st * 5120 + (8 + esf) * 512 + (er + 32 * ehh) * 8] = pk;
    }
    __syncthreads();
    if (m0 + 64 < N) prefetch(ms0 + 64);

    f32x16 S;
#pragma unroll
    for (int r = 0; r < 16; ++r) S[r] = 0.f;
    const short* vmh = &L[OFF_VMH3 + st * 4096];
    const short* vml = &L[OFF_VML3 + st * 4096];
#pragma unroll
    for (int k = 0; k < 8; ++k) {
      bf16x8 ah = *(const bf16x8*)&vmh[k * 512 + ln * 8];
      bf16x8 al = *(const bf16x8*)&vml[k * 512 + ln * 8];
      S = __builtin_amdgcn_mfma_f32_32x32x16_bf16(al, Qh[k], S, 0, 0, 0);
      S = __builtin_amdgcn_mfma_f32_32x32x16_bf16(ah, Ql[k], S, 0, 0, 0);
      S = __builtin_amdgcn_mfma_f32_32x32x16_bf16(ah, Qh[k], S, 0, 0, 0);
    }
#pragma unroll
    for (int q = 0; q < 4; ++q) {
      float p0 = __expf(fmaf(S[4 * q + 0], 100.0f, -60.0f));
      float p1 = __expf(fmaf(S[4 * q + 1], 100.0f, -60.0f));
      float p2 = __expf(fmaf(S[4 * q + 2], 100.0f, -60.0f));
      float p3 = __expf(fmaf(S[4 * q + 3], 100.0f, -60.0f));
      int2 a;
      a.x = rne2(p0, p1);
      a.y = rne2(p2, p3);
      *(int2*)&L[OFF_PH3 + w * 1024 + (q >> 1) * 512 + (l31 + 32 * (q & 1)) * 8 + h * 4] = a;
    }
#pragma unroll
    for (int s2 = 0; s2 < 2; ++s2) {
      bf16x8 bh = *(const bf16x8*)&L[OFF_PH3 + w * 1024 + s2 * 512 + ln * 8];
#pragma unroll
      for (int t = 0; t < 5; ++t) {
        bf16x8 va = *(const bf16x8*)&L[OFF_VCM3 + st * 5120 + (2 * t + s2) * 512 + ln * 8];
        acc[t] = __builtin_amdgcn_mfma_f32_32x32x16_bf16(va, bh, acc[t], 0, 0, 0);
      }
    }
    __syncthreads();
  }

  float* red = (float*)&L[0];
  if (st == 1) {
#pragma unroll
    for (int t = 0; t < 5; ++t)
#pragma unroll
      for (int r = 0; r < 16; ++r)
        red[wn * 5120 + t * 1024 + r * 64 + ln] = acc[t][r];
  }
  __syncthreads();
  if (st == 0) {
#pragma unroll
    for (int t = 0; t < 5; ++t)
#pragma unroll
      for (int r = 0; r < 16; ++r)
        acc[t][r] += red[wn * 5120 + t * 1024 + r * 64 + ln];
    float ssqd = 0.f, dotr = 0.f;
#pragma unroll
    for (int t = 0; t < 4; ++t) {
#pragma unroll
      for (int r = 0; r < 16; ++r) {
        int c = 32 * t + (r & 3) + 8 * (r >> 2) + 4 * h;
        float d = acc[t][r];
        ssqd = fmaf(d, d, ssqd);
        dotr = fmaf(d, srcd[(size_t)c * N + nn], dotr);
      }
    }
    ssqd += __shfl_xor(ssqd, 32);
    dotr += __shfl_xor(dotr, 32);
    if (h == 0) {
      float x = acc[4][0], y = acc[4][1], wv = acc[4][2], Ld = acc[4][3];
      float invL = 1.0f / Ld;
      float nrm = fmaxf(sqrtf(ssqd), 1e-30f);
      float score = dotr / (nrm * 128.0f);
      float sw = wtsp[(size_t)sb * N + nn];
      out[(size_t)p * 2 * N + nn] = x * invL;
      out[(size_t)p * 2 * N + N + nn] = y * invL;
      out[(size_t)(BP * 2 * N) + (size_t)p * N + nn] =
          0.5f * (score + 1.0f) * sw * wv * invL;
    }
  }
}

extern "C" void kernel_launch(void* const* d_in, const int* in_sizes, int n_in,
                              void* d_out, int out_size, void* d_ws, size_t ws_size,
                              hipStream_t stream) {
  const float* coords = (const float*)d_in[0];  // [16][2][4096]
  const float* wts = (const float*)d_in[1];     // [16][1][4096]
  const float* desc = (const float*)d_in[2];    // [16][128][4096]
  float* out = (float*)d_out;                   // [8][2][4096] ++ [8][1][4096]
  float* inv = (float*)d_ws;                    // fallback inv-norms
  unsigned char* blob = (unsigned char*)d_ws + PREP_OFF;

  if (ws_size >= PREP_OFF + BLOB_BYTES) {
    kprep<<<dim3(128, BP), 256, 0, stream>>>(coords, wts, desc, blob);
    kmain<<<dim3((N / TN) * BP), 256, 0, stream>>>(wts, desc, blob, out);
  } else {
    knorm_inv<<<dim3(N / 256, BP), 256, 0, stream>>>(desc, inv);
    kmain_v3<<<dim3(N / TN, BP), 256, 0, stream>>>(coords, wts, desc, inv, out);
  }
}